// Round 19
// baseline (441.122 us; speedup 1.0000x reference)
//
#include <hip/hip_runtime.h>
#include <cstdint>
#include <cstddef>

typedef __attribute__((ext_vector_type(8))) short short8;   // 8 bf16 = 4 VGPR
typedef __attribute__((ext_vector_type(4))) float f32x4;    // MFMA acc
typedef __attribute__((ext_vector_type(4))) float flt4;

#define DEV __device__ __forceinline__

constexpr int C_ = 1024, E_ = 8, H_ = 2048, K_TOP = 2;
constexpr int N_ = 8192;              // B*T tokens
constexpr int NK_ = N_ * K_TOP;       // 16384 token-expert pairs
constexpr int HB_ = 32;               // histogram blocks (256 tokens each)

DEV unsigned short f2bf(float f){
  unsigned u = __float_as_uint(f);
  u += 0x7fffu + ((u >> 16) & 1u);    // round-to-nearest-even
  return (unsigned short)(u >> 16);
}

// async global->LDS, 16B per lane; LDS dest = wave-uniform base + lane*16
DEV void gload16(const void* g, void* l){
  __builtin_amdgcn_global_load_lds((const __attribute__((address_space(1))) unsigned int*)g,
                                   (__attribute__((address_space(3))) unsigned int*)l,
                                   16, 0, 0);
}

// ---- x fp32 -> bf16, 8 elems/thread --------------------------------------
__global__ void cvt_x_kernel(const float* __restrict__ s, unsigned short* __restrict__ d){
  size_t i = ((size_t)blockIdx.x * blockDim.x + threadIdx.x) * 8;
  flt4 v0 = *(const flt4*)(s + i);
  flt4 v1 = *(const flt4*)(s + i + 4);
  short8 o;
  o[0]=f2bf(v0[0]); o[1]=f2bf(v0[1]); o[2]=f2bf(v0[2]); o[3]=f2bf(v0[3]);
  o[4]=f2bf(v1[0]); o[5]=f2bf(v1[1]); o[6]=f2bf(v1[2]); o[7]=f2bf(v1[3]);
  *(short8*)(d + i) = o;
}

// ---- transpose-convert (E,R,S) f32 -> (E,S,R) bf16 -----------------------
__global__ void tconv_kernel(const float* __restrict__ src, unsigned short* __restrict__ dst,
                             int R, int S){
  __shared__ float tile[32][33];      // +1 pad: conflict-free transpose
  int e = blockIdx.z;
  int r0 = blockIdx.y * 32, s0 = blockIdx.x * 32;
  const float* se = src + (size_t)e * R * S;
  unsigned short* de = dst + (size_t)e * R * S;
  int tx = threadIdx.x & 31, ty = threadIdx.x >> 5;
  #pragma unroll
  for (int i = 0; i < 4; i++){
    int r = ty + i * 8;
    tile[r][tx] = se[(size_t)(r0 + r) * S + s0 + tx];
  }
  __syncthreads();
  #pragma unroll
  for (int i = 0; i < 4; i++){
    int s = ty + i * 8;
    de[(size_t)(s0 + s) * R + r0 + tx] = f2bf(tile[tx][s]);
  }
}

// ---- gate: logits -> softmax -> top2 (NO global atomics) -----------------
__global__ void gate_kernel(const float* __restrict__ x, const float* __restrict__ gw,
                            const float* __restrict__ gb,
                            int* __restrict__ tok_e, float* __restrict__ tok_g){
  int lane = threadIdx.x & 63;
  int n = blockIdx.x * 4 + (threadIdx.x >> 6);   // 1 wave per token
  const float* xr = x + (size_t)n * C_;
  float acc[E_];
  #pragma unroll
  for (int e = 0; e < E_; e++) acc[e] = 0.f;
  #pragma unroll 4
  for (int j = 0; j < C_ / 64; j++){
    int c = lane + j * 64;
    float xv = xr[c];
    flt4 g0 = *(const flt4*)(gw + (size_t)c * E_);
    flt4 g1 = *(const flt4*)(gw + (size_t)c * E_ + 4);
    acc[0] += xv * g0[0]; acc[1] += xv * g0[1]; acc[2] += xv * g0[2]; acc[3] += xv * g0[3];
    acc[4] += xv * g1[0]; acc[5] += xv * g1[1]; acc[6] += xv * g1[2]; acc[7] += xv * g1[3];
  }
  #pragma unroll
  for (int e = 0; e < E_; e++)
    #pragma unroll
    for (int off = 32; off > 0; off >>= 1)
      acc[e] += __shfl_xor(acc[e], off, 64);
  if (lane == 0){
    float l[E_], p[E_];
    float m = -1e30f;
    #pragma unroll
    for (int e = 0; e < E_; e++){ l[e] = acc[e] + gb[e]; m = fmaxf(m, l[e]); }
    float s = 0.f;
    #pragma unroll
    for (int e = 0; e < E_; e++){ p[e] = expf(l[e] - m); s += p[e]; }
    float inv = 1.f / s;
    int e0 = 0; float m0 = p[0];
    #pragma unroll
    for (int e = 1; e < E_; e++) if (p[e] > m0){ m0 = p[e]; e0 = e; }  // strict >: lowest idx on tie (jax)
    int e1 = -1; float m1 = -1.f;
    #pragma unroll
    for (int e = 0; e < E_; e++) if (e != e0 && p[e] > m1){ m1 = p[e]; e1 = e; }
    tok_e[2*n]   = e0; tok_g[2*n]   = m0 * inv;
    tok_e[2*n+1] = e1; tok_g[2*n+1] = m1 * inv;
  }
}

// ---- per-block LDS histogram: no global atomics --------------------------
__global__ void hist_kernel(const int* __restrict__ tok_e, int* __restrict__ blockhist){
  __shared__ int h[E_];
  if (threadIdx.x < E_) h[threadIdx.x] = 0;
  __syncthreads();
  int n = blockIdx.x * 256 + threadIdx.x;
  int e0 = tok_e[2*n], e1 = tok_e[2*n+1];
  atomicAdd(&h[e0], 1);
  atomicAdd(&h[e1], 1);
  __syncthreads();
  if (threadIdx.x < E_) blockhist[blockIdx.x * E_ + threadIdx.x] = h[threadIdx.x];
}

// ---- serial scan over 32x8 block histograms (trivial) --------------------
__global__ void scan2_kernel(const int* __restrict__ blockhist, int* __restrict__ counts,
                             int* __restrict__ offsets, int* __restrict__ blockbase){
  if (threadIdx.x == 0){
    int tot[E_];
    for (int e = 0; e < E_; e++){
      int s = 0;
      for (int b = 0; b < HB_; b++) s += blockhist[b * E_ + e];
      tot[e] = s;
    }
    int s = 0;
    for (int e = 0; e < E_; e++){ counts[e] = tot[e]; offsets[e] = s; s += tot[e]; }
    for (int e = 0; e < E_; e++){
      int cur = offsets[e];
      for (int b = 0; b < HB_; b++){ blockbase[b * E_ + e] = cur; cur += blockhist[b * E_ + e]; }
    }
  }
}

// ---- build compacted lists: LDS cursors seeded from blockbase ------------
__global__ void build_kernel(const int* __restrict__ tok_e, const float* __restrict__ tok_g,
                             const int* __restrict__ blockbase,
                             int* __restrict__ list_tok, float* __restrict__ list_gate){
  __shared__ int cur[E_];
  if (threadIdx.x < E_) cur[threadIdx.x] = blockbase[blockIdx.x * E_ + threadIdx.x];
  __syncthreads();
  int n = blockIdx.x * 256 + threadIdx.x;
  #pragma unroll
  for (int k = 0; k < K_TOP; k++){
    int e = tok_e[2*n + k];
    int pos = atomicAdd(&cur[e], 1);     // LDS atomic: cheap
    list_tok[pos] = n;
    list_gate[pos] = tok_g[2*n + k];
  }
}

// ---- grouped GEMM: 256x256, T3 "minimum 2-phase" recipe (m248: 655 TF) ---
// Faithful port of the guide's T3 recipe at 256^2, BK=64, 8 waves (2Mx4N,
// wave tile 128x64, acc[8][4]): per iter t:
//   STAGE(t+1 -> buf[(t+1)&1])   (8 gload16/thread, issued FIRST)
//   per s in {0,1}: 12 ds_read_b128 -> lgkmcnt(0) -> sched_barrier(0)
//                   (rule #18: fence MFMA hoisting) -> setprio(1) ->
//                   32 MFMA -> setprio(0)
//   vmcnt(0)  (t+1's loads landed; covered by this iter's reads+MFMA)
//   s_barrier (buffer handoff)
// Liveness: buf[(t+1)&1] last read at iter t-1; those ds_reads retire
// before their MFMAs (lgkmcnt 0), which precede iter t-1's barrier, which
// precedes this STAGE. buf[t&1] fully staged: drained by iter t-1's
// vmcnt(0)+barrier. 128 KB LDS -> 1 block/CU (expected; m248 proves the
// recipe performs there). Swizzle = proven involution (rule #21): store
// chunk (tid&7)^(row&7), read chunk (s*4+lk)^(lr&7); 16-lane read quarters
// -> 2-way banking (free, m136; measured 0 conflicts R5-R18).
// GEMM2 K-split x2 (R11 mapping, correctness-proven): 512 active blocks
// both GEMMs. XCD-chunk bijective swizzle: expert == XCD (FETCH 287->65MB).
// FIRST:  h[pos,H] = relu(X[tok] @ w1t[e]^T + b1[e]), A=xb gathered, B=w1t (E,H,C)
// !FIRST: out[tok] += gate * (h[pos](ks) @ w2t[e](ks)^T + [ks==0]b2[e])
template<bool FIRST>
__global__ __launch_bounds__(512, 2)
void moe_gemm(const unsigned short* __restrict__ Abase,
              const unsigned short* __restrict__ Bbase,
              const float* __restrict__ bias,
              const int* __restrict__ counts, const int* __restrict__ offsets,
              const int* __restrict__ list_tok, const float* __restrict__ list_gate,
              unsigned short* __restrict__ hbuf, float* __restrict__ out){
  constexpr int K    = FIRST ? C_ : H_;     // A/B row stride
  constexpr int Ksub = 1024;                // K per block
  constexpr int NT   = Ksub / 64;           // 16
  constexpr int ND   = FIRST ? H_ : C_;
  constexpr int GX   = FIRST ? 8 : 4;       // 256-col tiles
  __shared__ unsigned char smem[131072];    // 2 x ( A[256][128B] | B[256][128B] )

  // bijective XCD-chunk swizzle: nwg = 2048 both GEMMs, chunk 256 = 1 expert
  int lin  = blockIdx.x + GX * (blockIdx.y + 32 * blockIdx.z);
  int work = (lin & 7) * 256 + (lin >> 3);
  int bx, by, e, ks;
  if (FIRST){
    bx = work & 7; by = (work >> 3) & 31; e = work >> 8; ks = 0;
  } else {
    bx = work & 3; by = (work >> 2) & 31; int rem = work >> 7; e = rem >> 1; ks = rem & 1;
  }

  int ne = counts[e];
  int row0 = by * 256;
  if (row0 >= ne) return;                   // worst-case grid, early exit
  int off = offsets[e];
  int col0 = bx * 256;
  int tid = threadIdx.x;
  int lane = tid & 63, wave = tid >> 6;     // 8 waves
  int wm = wave >> 2, wn = wave & 3;        // 2M x 4N, wave tile 128x64
  int lr = lane & 15, lk = lane >> 4;
  int rr = tid >> 3;                        // 0..63
  int chunk = (tid & 7) ^ (rr & 7);         // global-side swizzle (rule #21)

  const unsigned short* Bexp = Bbase + (size_t)e * ND * K;
  const unsigned short* agsrc[4];
  const unsigned short* bgsrc[4];
  #pragma unroll
  for (int j = 0; j < 4; j++){
    int r = j * 64 + rr;                    // 0..255
    int rc = min(row0 + r, ne - 1);
    size_t arow = FIRST ? (size_t)list_tok[off + rc] * C_ : (size_t)(off + rc) * H_;
    agsrc[j] = Abase + arow + ks * Ksub + chunk * 8;
    bgsrc[j] = Bexp + (size_t)(col0 + r) * K + ks * Ksub + chunk * 8;
  }
  unsigned char* AdW = smem + wave * 1024;           // + buf*65536 + j*8192
  unsigned char* BdW = smem + 32768 + wave * 1024;

  f32x4 acc[8][4];
  #pragma unroll
  for (int a = 0; a < 8; a++)
    #pragma unroll
    for (int b = 0; b < 4; b++) acc[a][b] = (f32x4){0.f,0.f,0.f,0.f};

  #define STAGE(t) do{                                               \
    int _b = ((t) & 1) * 65536;                                      \
    int _kn = (t) * 64;                                              \
    _Pragma("unroll")                                                \
    for (int _j = 0; _j < 4; _j++){                                  \
      gload16(agsrc[_j] + _kn, AdW + _b + _j * 8192);                \
      gload16(bgsrc[_j] + _kn, BdW + _b + _j * 8192);                \
    }                                                                \
  }while(0)

  // prologue
  STAGE(0);
  asm volatile("s_waitcnt vmcnt(0)" ::: "memory");
  __builtin_amdgcn_s_barrier();
  __builtin_amdgcn_sched_barrier(0);

  for (int t = 0; t < NT; ++t){
    if (t + 1 < NT) STAGE(t + 1);           // issue next-tile loads FIRST
    const unsigned char* Ab = smem + (t & 1) * 65536;
    const unsigned char* Bb = Ab + 32768;
    #pragma unroll
    for (int s = 0; s < 2; s++){
      short8 av[8], bv[4];
      int kx = ((s * 4 + lk) ^ (lr & 7)) * 16;    // swizzled chunk byte
      #pragma unroll
      for (int m = 0; m < 8; m++)
        av[m] = *(const short8*)(Ab + (wm * 128 + m * 16 + lr) * 128 + kx);
      #pragma unroll
      for (int n = 0; n < 4; n++)
        bv[n] = *(const short8*)(Bb + (wn * 64 + n * 16 + lr) * 128 + kx);
      asm volatile("s_waitcnt lgkmcnt(0)" ::: "memory");
      __builtin_amdgcn_sched_barrier(0);     // rule #18: MFMA must not hoist
      __builtin_amdgcn_s_setprio(1);
      #pragma unroll
      for (int m = 0; m < 8; m++)
        #pragma unroll
        for (int n = 0; n < 4; n++)
          acc[m][n] = __builtin_amdgcn_mfma_f32_16x16x32_bf16(av[m], bv[n], acc[m][n], 0, 0, 0);
      __builtin_amdgcn_s_setprio(0);
    }
    asm volatile("s_waitcnt vmcnt(0)" ::: "memory");  // next tile landed
    __builtin_amdgcn_s_barrier();
    __builtin_amdgcn_sched_barrier(0);
  }
  #undef STAGE

  if (FIRST){
    #pragma unroll
    for (int m = 0; m < 8; m++){
      int rbase = row0 + wm*128 + m*16 + lk*4;      // D: row=(l>>4)*4+i, col=l&15
      #pragma unroll
      for (int n = 0; n < 4; n++){
        int colb = col0 + wn*64 + n*16 + lr;
        float bv2 = bias[e*ND + colb];
        #pragma unroll
        for (int i = 0; i < 4; i++){
          int r = rbase + i;
          if (r < ne){
            float v = acc[m][n][i] + bv2;
            v = v > 0.f ? v : 0.f;
            hbuf[(size_t)(off + r)*H_ + colb] = f2bf(v);
          }
        }
      }
    }
  } else {
    #pragma unroll
    for (int m = 0; m < 8; m++){
      int rbase = row0 + wm*128 + m*16 + lk*4;
      #pragma unroll
      for (int i = 0; i < 4; i++){
        int r = rbase + i;
        if (r < ne){
          int pos = off + r;
          int tok = list_tok[pos];
          float g = list_gate[pos];
          float* orow = out + (size_t)tok * C_;
          #pragma unroll
          for (int n = 0; n < 4; n++){
            int colb = col0 + wn*64 + n*16 + lr;
            float bterm = ks == 0 ? bias[e*ND + colb] : 0.f;
            float v = (acc[m][n][i] + bterm) * g;
            atomicAdd(orow + colb, v);   // commutative adds per out elem
          }
        }
      }
    }
  }
}

extern "C" void kernel_launch(void* const* d_in, const int* in_sizes, int n_in,
                              void* d_out, int out_size, void* d_ws, size_t ws_size,
                              hipStream_t stream){
  const float* x  = (const float*)d_in[0];
  const float* gw = (const float*)d_in[1];
  const float* gb = (const float*)d_in[2];
  const float* w1 = (const float*)d_in[3];
  const float* b1 = (const float*)d_in[4];
  const float* w2 = (const float*)d_in[5];
  const float* b2 = (const float*)d_in[6];
  float* out = (float*)d_out;

  // workspace carve-up (~144.5 MB total)
  char* p = (char*)d_ws;
  unsigned short* xb   = (unsigned short*)p; p += (size_t)N_*C_*2;     // 16 MB
  unsigned short* w1t  = (unsigned short*)p; p += (size_t)E_*C_*H_*2;  // 32 MB (E,H,C)
  unsigned short* w2t  = (unsigned short*)p; p += (size_t)E_*C_*H_*2;  // 32 MB (E,C,H)
  unsigned short* hbuf = (unsigned short*)p; p += (size_t)NK_*H_*2;    // 64 MB
  int*   tok_e     = (int*)p;   p += (size_t)NK_*4;
  float* tok_g     = (float*)p; p += (size_t)NK_*4;
  int*   list_tok  = (int*)p;   p += (size_t)NK_*4;
  float* list_gate = (float*)p; p += (size_t)NK_*4;
  int*   counts    = (int*)p;   p += 256;
  int*   offsets   = (int*)p;   p += 256;
  int*   blockhist = (int*)p;   p += HB_*E_*4;
  int*   blockbase = (int*)p;   p += HB_*E_*4;

  hipMemsetAsync(out, 0, (size_t)out_size * sizeof(float), stream);

  cvt_x_kernel<<<(N_*C_/8)/256, 256, 0, stream>>>(x, xb);
  tconv_kernel<<<dim3(H_/32, C_/32, E_), 256, 0, stream>>>(w1, w1t, C_, H_);
  tconv_kernel<<<dim3(C_/32, H_/32, E_), 256, 0, stream>>>(w2, w2t, H_, C_);
  gate_kernel<<<N_/4, 256, 0, stream>>>(x, gw, gb, tok_e, tok_g);
  hist_kernel<<<HB_, 256, 0, stream>>>(tok_e, blockhist);
  scan2_kernel<<<1, 64, 0, stream>>>(blockhist, counts, offsets, blockbase);
  build_kernel<<<HB_, 256, 0, stream>>>(tok_e, tok_g, blockbase, list_tok, list_gate);

  moe_gemm<true ><<<dim3(8, 32, 8),  512, 0, stream>>>(xb,   w1t, b1, counts, offsets, list_tok, list_gate, hbuf, out);
  moe_gemm<false><<<dim3(4, 32, 16), 512, 0, stream>>>(hbuf, w2t, b2, counts, offsets, list_tok, list_gate, hbuf, out);
}

// Round 20
// 326.781 us; speedup vs baseline: 1.3499x; 1.3499x over previous
//
#include <hip/hip_runtime.h>
#include <cstdint>
#include <cstddef>

typedef __attribute__((ext_vector_type(8))) short short8;   // 8 bf16 = 4 VGPR
typedef __attribute__((ext_vector_type(4))) float f32x4;    // MFMA acc
typedef __attribute__((ext_vector_type(4))) float flt4;

#define DEV __device__ __forceinline__

constexpr int C_ = 1024, E_ = 8, H_ = 2048, K_TOP = 2;
constexpr int N_ = 8192;              // B*T tokens
constexpr int NK_ = N_ * K_TOP;       // 16384 token-expert pairs
constexpr int HB_ = 32;               // histogram blocks (256 tokens each)

DEV unsigned short f2bf(float f){
  unsigned u = __float_as_uint(f);
  u += 0x7fffu + ((u >> 16) & 1u);    // round-to-nearest-even
  return (unsigned short)(u >> 16);
}

// async global->LDS, 16B per lane; LDS dest = wave-uniform base + lane*16
DEV void gload16(const void* g, void* l){
  __builtin_amdgcn_global_load_lds((const __attribute__((address_space(1))) unsigned int*)g,
                                   (__attribute__((address_space(3))) unsigned int*)l,
                                   16, 0, 0);
}

// ---- transpose-convert (E,R,S) f32 -> (E,S,R) bf16 -----------------------
__global__ void tconv_kernel(const float* __restrict__ src, unsigned short* __restrict__ dst,
                             int R, int S){
  __shared__ float tile[32][33];      // +1 pad: conflict-free transpose
  int e = blockIdx.z;
  int r0 = blockIdx.y * 32, s0 = blockIdx.x * 32;
  const float* se = src + (size_t)e * R * S;
  unsigned short* de = dst + (size_t)e * R * S;
  int tx = threadIdx.x & 31, ty = threadIdx.x >> 5;
  #pragma unroll
  for (int i = 0; i < 4; i++){
    int r = ty + i * 8;
    tile[r][tx] = se[(size_t)(r0 + r) * S + s0 + tx];
  }
  __syncthreads();
  #pragma unroll
  for (int i = 0; i < 4; i++){
    int s = ty + i * 8;
    de[(size_t)(s0 + s) * R + r0 + tx] = f2bf(tile[tx][s]);
  }
}

// ---- gate: logits -> softmax -> top2; ALSO emits xb (bf16 of x) ----------
// Fusion: each wave touches its token's 1024 x-elements exactly once ->
// write the bf16 conversion inline, eliminating the separate cvt_x kernel
// (saves one 32 MB read of x). No global atomics.
__global__ void gate_kernel(const float* __restrict__ x, const float* __restrict__ gw,
                            const float* __restrict__ gb,
                            unsigned short* __restrict__ xb,
                            int* __restrict__ tok_e, float* __restrict__ tok_g){
  int lane = threadIdx.x & 63;
  int n = blockIdx.x * 4 + (threadIdx.x >> 6);   // 1 wave per token
  const float* xr = x + (size_t)n * C_;
  unsigned short* xbr = xb + (size_t)n * C_;
  float acc[E_];
  #pragma unroll
  for (int e = 0; e < E_; e++) acc[e] = 0.f;
  #pragma unroll 4
  for (int j = 0; j < C_ / 64; j++){
    int c = lane + j * 64;
    float xv = xr[c];
    xbr[c] = f2bf(xv);                           // fused bf16 emit (coalesced)
    flt4 g0 = *(const flt4*)(gw + (size_t)c * E_);
    flt4 g1 = *(const flt4*)(gw + (size_t)c * E_ + 4);
    acc[0] += xv * g0[0]; acc[1] += xv * g0[1]; acc[2] += xv * g0[2]; acc[3] += xv * g0[3];
    acc[4] += xv * g1[0]; acc[5] += xv * g1[1]; acc[6] += xv * g1[2]; acc[7] += xv * g1[3];
  }
  #pragma unroll
  for (int e = 0; e < E_; e++)
    #pragma unroll
    for (int off = 32; off > 0; off >>= 1)
      acc[e] += __shfl_xor(acc[e], off, 64);
  if (lane == 0){
    float l[E_], p[E_];
    float m = -1e30f;
    #pragma unroll
    for (int e = 0; e < E_; e++){ l[e] = acc[e] + gb[e]; m = fmaxf(m, l[e]); }
    float s = 0.f;
    #pragma unroll
    for (int e = 0; e < E_; e++){ p[e] = expf(l[e] - m); s += p[e]; }
    float inv = 1.f / s;
    int e0 = 0; float m0 = p[0];
    #pragma unroll
    for (int e = 1; e < E_; e++) if (p[e] > m0){ m0 = p[e]; e0 = e; }  // strict >: lowest idx on tie (jax)
    int e1 = -1; float m1 = -1.f;
    #pragma unroll
    for (int e = 0; e < E_; e++) if (e != e0 && p[e] > m1){ m1 = p[e]; e1 = e; }
    tok_e[2*n]   = e0; tok_g[2*n]   = m0 * inv;
    tok_e[2*n+1] = e1; tok_g[2*n+1] = m1 * inv;
  }
}

// ---- per-block LDS histogram: no global atomics --------------------------
__global__ void hist_kernel(const int* __restrict__ tok_e, int* __restrict__ blockhist){
  __shared__ int h[E_];
  if (threadIdx.x < E_) h[threadIdx.x] = 0;
  __syncthreads();
  int n = blockIdx.x * 256 + threadIdx.x;
  int e0 = tok_e[2*n], e1 = tok_e[2*n+1];
  atomicAdd(&h[e0], 1);
  atomicAdd(&h[e1], 1);
  __syncthreads();
  if (threadIdx.x < E_) blockhist[blockIdx.x * E_ + threadIdx.x] = h[threadIdx.x];
}

// ---- serial scan over 32x8 block histograms (trivial) --------------------
__global__ void scan2_kernel(const int* __restrict__ blockhist, int* __restrict__ counts,
                             int* __restrict__ offsets, int* __restrict__ blockbase){
  if (threadIdx.x == 0){
    int tot[E_];
    for (int e = 0; e < E_; e++){
      int s = 0;
      for (int b = 0; b < HB_; b++) s += blockhist[b * E_ + e];
      tot[e] = s;
    }
    int s = 0;
    for (int e = 0; e < E_; e++){ counts[e] = tot[e]; offsets[e] = s; s += tot[e]; }
    for (int e = 0; e < E_; e++){
      int cur = offsets[e];
      for (int b = 0; b < HB_; b++){ blockbase[b * E_ + e] = cur; cur += blockhist[b * E_ + e]; }
    }
  }
}

// ---- build compacted lists: LDS cursors seeded from blockbase ------------
__global__ void build_kernel(const int* __restrict__ tok_e, const float* __restrict__ tok_g,
                             const int* __restrict__ blockbase,
                             int* __restrict__ list_tok, float* __restrict__ list_gate){
  __shared__ int cur[E_];
  if (threadIdx.x < E_) cur[threadIdx.x] = blockbase[blockIdx.x * E_ + threadIdx.x];
  __syncthreads();
  int n = blockIdx.x * 256 + threadIdx.x;
  #pragma unroll
  for (int k = 0; k < K_TOP; k++){
    int e = tok_e[2*n + k];
    int pos = atomicAdd(&cur[e], 1);     // LDS atomic: cheap
    list_tok[pos] = n;
    list_gate[pos] = tok_g[2*n + k];
  }
}

// ---- grouped GEMM: R13 (session best: 147us/GEMM, 467 TF) ----------------
// 16-variant ledger: this exact structure beats every deviation tried
// {256^2 x4, BK=128, BK-split, direct-B, persistent, dbuf, depth-3 ring,
// 8-wave, A-reuse, occupancy forcing x2} by 8-70%. Plateau is the
// 2-barrier step's latency chain (~2750 cyc/CU-step), invariant under
// waves/depth/transaction-size. Components: 128^2 tile, BK=64, 4 waves
// (2x2), 2-barrier K-loop, global_load_lds both operands, both-sides
// chunk-XOR swizzle (rule #21, conflict-0 measured), bijective XCD-chunk
// blockIdx swizzle (expert==XCD; FETCH 287->65 MB measured).
// FIRST:  h[pos,H] = relu(X[tok] @ w1t[e]^T + b1[e]), A=xb gathered, B=w1t (E,H,C)
// !FIRST: out[tok] += gate * (h[pos] @ w2t[e]^T + b2[e]),  A=hbuf,   B=w2t (E,C,H)
template<bool FIRST>
__global__ __launch_bounds__(256, 3)
void moe_gemm(const unsigned short* __restrict__ Abase,
              const unsigned short* __restrict__ Bbase,
              const float* __restrict__ bias,
              const int* __restrict__ counts, const int* __restrict__ offsets,
              const int* __restrict__ list_tok, const float* __restrict__ list_gate,
              unsigned short* __restrict__ hbuf, float* __restrict__ out){
  constexpr int K   = FIRST ? C_ : H_;
  constexpr int ND  = FIRST ? H_ : C_;
  constexpr int GX  = ND / 128;            // 16 (GEMM1) / 8 (GEMM2), pow2
  constexpr int LGX = FIRST ? 4 : 3;
  constexpr int GY  = N_ / 128;            // 64 (6 bits)
  __shared__ unsigned char smem[32768];    // A: [0,16K), B: [16K,32K)

  // bijective XCD-chunk swizzle (nwg = GX*GY*8): lin%8 == chunk == expert
  int lin  = blockIdx.x + GX * (blockIdx.y + GY * blockIdx.z);
  int work = (lin & 7) * (GX * GY) + (lin >> 3);
  int bx = work & (GX - 1);
  int by = (work >> LGX) & (GY - 1);
  int e  = work >> (LGX + 6);

  int ne = counts[e];
  int row0 = by * 128;
  if (row0 >= ne) return;                   // worst-case grid, early exit
  int off = offsets[e];
  int col0 = bx * 128;
  int tid = threadIdx.x;
  int lane = tid & 63, wave = tid >> 6;     // 4 waves
  int wm = wave >> 1, wn = wave & 1;        // 2 x 2
  int lr = lane & 15, lk = lane >> 4;
  int rr = tid >> 3;
  int chunk = (tid & 7) ^ (rr & 7);         // global-side swizzle (rule #21)

  const unsigned short* Bexp = Bbase + (size_t)e * ND * K;
  const unsigned short* agsrc[4];
  const unsigned short* bgsrc[4];
  #pragma unroll
  for (int j = 0; j < 4; j++){
    int r = j * 32 + rr;
    int rc = min(row0 + r, ne - 1);
    size_t arow = FIRST ? (size_t)list_tok[off + rc] * C_ : (size_t)(off + rc) * H_;
    agsrc[j] = Abase + arow + chunk * 8;
    bgsrc[j] = Bexp + (size_t)(col0 + r) * K + chunk * 8;
  }
  unsigned char* Adst = smem + wave * 1024;
  unsigned char* Bdst = smem + 16384 + wave * 1024;

  f32x4 acc[4][4];
  #pragma unroll
  for (int a = 0; a < 4; a++)
    #pragma unroll
    for (int b = 0; b < 4; b++) acc[a][b] = (f32x4){0.f,0.f,0.f,0.f};

  for (int k0 = 0; k0 < K; k0 += 64){
    __syncthreads();                        // previous compute done
    #pragma unroll
    for (int j = 0; j < 4; j++) gload16(agsrc[j] + k0, Adst + j * 4096);
    #pragma unroll
    for (int j = 0; j < 4; j++) gload16(bgsrc[j] + k0, Bdst + j * 4096);
    __syncthreads();                        // drains vmcnt -> LDS ready
    #pragma unroll
    for (int s = 0; s < 2; s++){
      short8 av[4], bv[4];
      int kx = ((s * 4 + lk) ^ (lr & 7)) * 16;    // swizzled chunk byte
      #pragma unroll
      for (int fm = 0; fm < 4; fm++){
        int row = wm * 64 + fm * 16 + lr;
        av[fm] = *(const short8*)(smem + row * 128 + kx);
      }
      #pragma unroll
      for (int fn = 0; fn < 4; fn++){
        int col = wn * 64 + fn * 16 + lr;
        bv[fn] = *(const short8*)(smem + 16384 + col * 128 + kx);
      }
      #pragma unroll
      for (int fm = 0; fm < 4; fm++)
        #pragma unroll
        for (int fn = 0; fn < 4; fn++)
          acc[fm][fn] = __builtin_amdgcn_mfma_f32_16x16x32_bf16(av[fm], bv[fn], acc[fm][fn], 0, 0, 0);
    }
  }

  if (FIRST){
    #pragma unroll
    for (int fm = 0; fm < 4; fm++){
      int rbase = row0 + wm*64 + fm*16 + lk*4;      // D: row=(l>>4)*4+i, col=l&15
      #pragma unroll
      for (int fn = 0; fn < 4; fn++){
        int colb = col0 + wn*64 + fn*16 + lr;
        float bv2 = bias[e*ND + colb];
        #pragma unroll
        for (int i = 0; i < 4; i++){
          int r = rbase + i;
          if (r < ne){
            float v = acc[fm][fn][i] + bv2;
            v = v > 0.f ? v : 0.f;
            hbuf[(size_t)(off + r)*H_ + colb] = f2bf(v);
          }
        }
      }
    }
  } else {
    #pragma unroll
    for (int fm = 0; fm < 4; fm++){
      int rbase = row0 + wm*64 + fm*16 + lk*4;
      #pragma unroll
      for (int i = 0; i < 4; i++){
        int r = rbase + i;
        if (r < ne){
          int pos = off + r;
          int tok = list_tok[pos];
          float g = list_gate[pos];
          float* orow = out + (size_t)tok * C_;
          #pragma unroll
          for (int fn = 0; fn < 4; fn++){
            int colb = col0 + wn*64 + fn*16 + lr;
            float v = (acc[fm][fn][i] + bias[e*ND + colb]) * g;
            atomicAdd(orow + colb, v);   // exactly 2 adds per out elem -> deterministic
          }
        }
      }
    }
  }
}

extern "C" void kernel_launch(void* const* d_in, const int* in_sizes, int n_in,
                              void* d_out, int out_size, void* d_ws, size_t ws_size,
                              hipStream_t stream){
  const float* x  = (const float*)d_in[0];
  const float* gw = (const float*)d_in[1];
  const float* gb = (const float*)d_in[2];
  const float* w1 = (const float*)d_in[3];
  const float* b1 = (const float*)d_in[4];
  const float* w2 = (const float*)d_in[5];
  const float* b2 = (const float*)d_in[6];
  float* out = (float*)d_out;

  // workspace carve-up (~144.5 MB total)
  char* p = (char*)d_ws;
  unsigned short* xb   = (unsigned short*)p; p += (size_t)N_*C_*2;     // 16 MB
  unsigned short* w1t  = (unsigned short*)p; p += (size_t)E_*C_*H_*2;  // 32 MB (E,H,C)
  unsigned short* w2t  = (unsigned short*)p; p += (size_t)E_*C_*H_*2;  // 32 MB (E,C,H)
  unsigned short* hbuf = (unsigned short*)p; p += (size_t)NK_*H_*2;    // 64 MB
  int*   tok_e     = (int*)p;   p += (size_t)NK_*4;
  float* tok_g     = (float*)p; p += (size_t)NK_*4;
  int*   list_tok  = (int*)p;   p += (size_t)NK_*4;
  float* list_gate = (float*)p; p += (size_t)NK_*4;
  int*   counts    = (int*)p;   p += 256;
  int*   offsets   = (int*)p;   p += 256;
  int*   blockhist = (int*)p;   p += HB_*E_*4;
  int*   blockbase = (int*)p;   p += HB_*E_*4;

  hipMemsetAsync(out, 0, (size_t)out_size * sizeof(float), stream);

  gate_kernel<<<N_/4, 256, 0, stream>>>(x, gw, gb, xb, tok_e, tok_g);
  tconv_kernel<<<dim3(H_/32, C_/32, E_), 256, 0, stream>>>(w1, w1t, C_, H_);
  tconv_kernel<<<dim3(C_/32, H_/32, E_), 256, 0, stream>>>(w2, w2t, H_, C_);
  hist_kernel<<<HB_, 256, 0, stream>>>(tok_e, blockhist);
  scan2_kernel<<<1, 64, 0, stream>>>(blockhist, counts, offsets, blockbase);
  build_kernel<<<HB_, 256, 0, stream>>>(tok_e, tok_g, blockbase, list_tok, list_gate);

  moe_gemm<true ><<<dim3(H_/128, N_/128, E_), 256, 0, stream>>>(xb,   w1t, b1, counts, offsets, list_tok, list_gate, hbuf, out);
  moe_gemm<false><<<dim3(C_/128, N_/128, E_), 256, 0, stream>>>(hbuf, w2t, b2, counts, offsets, list_tok, list_gate, hbuf, out);
}